// Round 11
// baseline (698.305 us; speedup 1.0000x reference)
//
#include <hip/hip_runtime.h>

#define DMODEL 512
#define EPS_IN 1e-4f
#define EPS_LN 1e-5f
#define CLIPV  5.0f

typedef float f32x4 __attribute__((ext_vector_type(4)));
typedef short s16x8 __attribute__((ext_vector_type(8)));

__device__ __forceinline__ unsigned short f2bf(float f) {
    union { float f; unsigned u; } v; v.f = f;
    unsigned r = v.u + 0x7fffu + ((v.u >> 16) & 1u);
    return (unsigned short)(r >> 16);
}

struct TypeParams {
    const float* x;
    const float* ss;                   // scale[F] then shift[F]
    const unsigned short* Wt;          // [512][KP] bf16, zero-padded K
    const float* b; const float* gamma; const float* beta;
    int n;        // rows of this type
    int offset;   // row offset in concat order
    int nb;       // blocks (32-row tiles)
};

// Parts: [A] inv + tbatch/etype, [B] W -> Wt bf16 transpose, [C] scale/shift
__global__ __launch_bounds__(256) void setup_all(
    const int* __restrict__ index_map, const int* __restrict__ batch_index,
    int* __restrict__ inv, float* __restrict__ out_t, float* __restrict__ out_e,
    int total, int n0, int n01, int nbA,
    const float* __restrict__ W0, const float* __restrict__ W1, const float* __restrict__ W2,
    unsigned short* __restrict__ Wt0, unsigned short* __restrict__ Wt1, unsigned short* __restrict__ Wt2,
    const float* __restrict__ mean0, const float* __restrict__ var0,
    const float* __restrict__ mean1, const float* __restrict__ var1,
    const float* __restrict__ mean2, const float* __restrict__ var2,
    float* __restrict__ ss0, float* __restrict__ ss1, float* __restrict__ ss2)
{
    const int nbB = (DMODEL * 256) / 256;
    if (blockIdx.x < (unsigned)nbA) {
        const int j = blockIdx.x * 256 + threadIdx.x;
        if (j >= total) return;
        const int r = index_map[j];
        inv[r] = j;
        out_t[j] = (float)batch_index[r];
        out_e[j] = (r < n0) ? 0.0f : ((r < n01) ? 1.0f : 2.0f);
    } else if (blockIdx.x < (unsigned)(nbA + nbB)) {
        int idx = (blockIdx.x - nbA) * 256 + threadIdx.x;
        const float* W; unsigned short* Wt; int K, Kp;
        if (idx < DMODEL * 64)              { W = W0; Wt = Wt0; K = 64;  Kp = 64; }
        else if (idx < DMODEL * (64 + 128)) { idx -= DMODEL * 64;  W = W1; Wt = Wt1; K = 128; Kp = 128; }
        else                                { idx -= DMODEL * 192; W = W2; Wt = Wt2; K = 48;  Kp = 64; }
        const int nn = idx / Kp, k = idx - nn * Kp;
        const float w = (k < K) ? W[(size_t)k * DMODEL + nn] : 0.0f;
        Wt[idx] = f2bf(w);
    } else {
        const int c = threadIdx.x;
        if (c < 64)  { const float s = rsqrtf(var0[c] + EPS_IN); ss0[c] = s; ss0[64 + c]  = -mean0[c] * s; }
        if (c < 128) { const float s = rsqrtf(var1[c] + EPS_IN); ss1[c] = s; ss1[128 + c] = -mean1[c] * s; }
        if (c < 48)  { const float s = rsqrtf(var2[c] + EPS_IN); ss2[c] = s; ss2[48 + c]  = -mean2[c] * s; }
    }
}

// Block: 32 concat rows x 512 cols, 8 waves. Wave tile: 32 rows x 64 cols (wn).
// OPERAND-SWAPPED MFMA; LINEAR=true replaces the permuted store row with the
// concat row (ablation probe; inv load kept live for identical codegen).
template<int F, int KP, bool LINEAR>
__device__ __forceinline__ void embed_body(
    const TypeParams& p, int bid, const int* __restrict__ inv,
    float* __restrict__ out, char* lds)
{
    constexpr int SEG = KP / 8;
    constexpr int NKS = KP / 32;
    const int tid  = threadIdx.x;
    const int lane = tid & 63;
    const int wn   = tid >> 6;     // 0..7 (64-col slice)
    const int l15  = lane & 15;
    const int g    = lane >> 4;    // 0..3
    const int row0 = bid * 32;
    const int n    = p.n;

    float2* red = reinterpret_cast<float2*>(lds + NKS * 2048);  // [32 rows][8 wn]

    // ---- stage: InputNorm(x) -> bf16, fragment-order LDS (linear write)
    if (tid < 32 * SEG) {
        const int r = tid & 31;
        const int s = tid >> 5;
        const int c = s * 8;
        const int gr = row0 + r;
        s16x8 pk;
#pragma unroll
        for (int jj = 0; jj < 8; ++jj) pk[jj] = 0;
        if (gr < n && c < F) {
            const float4 x0 = *(const float4*)(p.x + (size_t)gr * F + c);
            const float4 x1 = *(const float4*)(p.x + (size_t)gr * F + c + 4);
            const float4 sc0 = *(const float4*)(p.ss + c);
            const float4 sc1 = *(const float4*)(p.ss + c + 4);
            const float4 sh0 = *(const float4*)(p.ss + F + c);
            const float4 sh1 = *(const float4*)(p.ss + F + c + 4);
            float t[8];
            t[0] = fmaf(x0.x, sc0.x, sh0.x); t[1] = fmaf(x0.y, sc0.y, sh0.y);
            t[2] = fmaf(x0.z, sc0.z, sh0.z); t[3] = fmaf(x0.w, sc0.w, sh0.w);
            t[4] = fmaf(x1.x, sc1.x, sh1.x); t[5] = fmaf(x1.y, sc1.y, sh1.y);
            t[6] = fmaf(x1.z, sc1.z, sh1.z); t[7] = fmaf(x1.w, sc1.w, sh1.w);
#pragma unroll
            for (int jj = 0; jj < 8; ++jj)
                pk[jj] = (short)f2bf(fminf(fmaxf(t[jj], -CLIPV), CLIPV));
        }
        *reinterpret_cast<s16x8*>(lds + tid * 16) = pk;
    }
    __syncthreads();

    // ---- destination rows (inv load always issued; probe keeps it alive)
    int orow[2];
#pragma unroll
    for (int m = 0; m < 2; ++m) {
        const int rg = row0 + m * 16 + l15;
        const int iv = (rg < n) ? inv[p.offset + rg] : -1;
        if (LINEAR) {
            asm volatile("" :: "v"(iv));
            orow[m] = (rg < n) ? (p.offset + rg) : -1;
        } else {
            orow[m] = iv;
        }
    }

    // ---- MFMA (operand-swapped)
    f32x4 acc[2][4];
#pragma unroll
    for (int m = 0; m < 2; ++m)
#pragma unroll
        for (int t = 0; t < 4; ++t) acc[m][t] = (f32x4)0.0f;

    const unsigned short* wtl = p.Wt + (size_t)(wn * 64 + l15) * KP + g * 8;

#pragma unroll
    for (int ks = 0; ks < NKS; ++ks) {
        const int ab = ((ks * 4 + g) * 32 + l15) * 16;
        const s16x8 a0 = *reinterpret_cast<const s16x8*>(lds + ab);
        const s16x8 a1 = *reinterpret_cast<const s16x8*>(lds + ab + 256);
#pragma unroll
        for (int t = 0; t < 4; ++t) {
            const s16x8 wf = *reinterpret_cast<const s16x8*>(wtl + (size_t)t * 16 * KP + ks * 32);
            acc[0][t] = __builtin_amdgcn_mfma_f32_16x16x32_bf16(wf, a0, acc[0][t], 0, 0, 0);
            acc[1][t] = __builtin_amdgcn_mfma_f32_16x16x32_bf16(wf, a1, acc[1][t], 0, 0, 0);
        }
    }

    // ---- bias + ReLU
#pragma unroll
    for (int t = 0; t < 4; ++t) {
        const float4 bb = *(const float4*)(p.b + wn * 64 + t * 16 + g * 4);
#pragma unroll
        for (int m = 0; m < 2; ++m) {
            acc[m][t][0] = fmaxf(acc[m][t][0] + bb.x, 0.0f);
            acc[m][t][1] = fmaxf(acc[m][t][1] + bb.y, 0.0f);
            acc[m][t][2] = fmaxf(acc[m][t][2] + bb.z, 0.0f);
            acc[m][t][3] = fmaxf(acc[m][t][3] + bb.w, 0.0f);
        }
    }

    // ---- LN partials: 2 rows/lane, g-reduce (2 shuffles), cross-wave via red
    {
        float ps[2] = {0.0f, 0.0f}, pq[2] = {0.0f, 0.0f};
#pragma unroll
        for (int m = 0; m < 2; ++m)
#pragma unroll
            for (int t = 0; t < 4; ++t)
#pragma unroll
                for (int j = 0; j < 4; ++j) {
                    const float v = acc[m][t][j];
                    ps[m] += v;
                    pq[m] = fmaf(v, v, pq[m]);
                }
#pragma unroll
        for (int m = 0; m < 2; ++m) {
            ps[m] += __shfl_xor(ps[m], 16, 64);
            pq[m] += __shfl_xor(pq[m], 16, 64);
            ps[m] += __shfl_xor(ps[m], 32, 64);
            pq[m] += __shfl_xor(pq[m], 32, 64);
        }
        if (g == 0) {
#pragma unroll
            for (int m = 0; m < 2; ++m)
                red[(m * 16 + l15) * 8 + wn] = make_float2(ps[m], pq[m]);
        }
    }
    __syncthreads();

    // ---- finish LN + float4 stores
#pragma unroll
    for (int m = 0; m < 2; ++m) {
        const int od = orow[m];
        if (od < 0) continue;
        const int rl = m * 16 + l15;
        float s = 0.0f, q = 0.0f;
#pragma unroll
        for (int wq = 0; wq < 8; ++wq) { const float2 e = red[rl * 8 + wq]; s += e.x; q += e.y; }
        const float mu = s * (1.0f / DMODEL);
        const float vv = fmaxf(q * (1.0f / DMODEL) - mu * mu, 0.0f);
        const float sc = rsqrtf(vv + EPS_LN);
        float* op = out + (size_t)od * DMODEL + wn * 64 + g * 4;
#pragma unroll
        for (int t = 0; t < 4; ++t) {
            const float4 gg = *(const float4*)(p.gamma + wn * 64 + t * 16 + g * 4);
            const float4 ee = *(const float4*)(p.beta  + wn * 64 + t * 16 + g * 4);
            float4 o;
            o.x = fmaf(gg.x * sc, acc[m][t][0] - mu, ee.x);
            o.y = fmaf(gg.y * sc, acc[m][t][1] - mu, ee.y);
            o.z = fmaf(gg.z * sc, acc[m][t][2] - mu, ee.z);
            o.w = fmaf(gg.w * sc, acc[m][t][3] - mu, ee.w);
            *(float4*)(op + t * 16) = o;
        }
    }
}

template<bool LINEAR>
__global__ __launch_bounds__(512, 4) void embed_all(
    TypeParams p0, TypeParams p1, TypeParams p2,
    const int* __restrict__ inv, float* __restrict__ out, int mod)
{
    extern __shared__ char lds[];
    const int bid = (int)(blockIdx.x % (unsigned)mod);
    if (bid < p0.nb)                embed_body<64, 64,  LINEAR>(p0, bid, inv, out, lds);
    else if (bid < p0.nb + p1.nb)   embed_body<128, 128, LINEAR>(p1, bid - p0.nb, inv, out, lds);
    else                            embed_body<48, 64,  LINEAR>(p2, bid - p0.nb - p1.nb, inv, out, lds);
}

extern "C" void kernel_launch(void* const* d_in, const int* in_sizes, int n_in,
                              void* d_out, int out_size, void* d_ws, size_t ws_size,
                              hipStream_t stream)
{
    const int F0 = 64, F1 = 128, F2 = 48;
    const int n0 = in_sizes[0]  / F0;
    const int n1 = in_sizes[7]  / F1;
    const int n2 = in_sizes[14] / F2;
    const int total = n0 + n1 + n2;

    float* out   = (float*)d_out;
    float* out_t = out + (size_t)total * DMODEL;
    float* out_e = out_t + total;

    // ws layout: inv[total] ints | Wt0/Wt1/Wt2 bf16 | ss0/ss1/ss2 f32 | probe out @32MB
    int* inv = (int*)d_ws;
    unsigned short* Wt0 = (unsigned short*)((char*)d_ws + (((size_t)total * 4 + 255) & ~(size_t)255));
    unsigned short* Wt1 = Wt0 + DMODEL * 64;
    unsigned short* Wt2 = Wt1 + DMODEL * 128;
    float* ss0 = (float*)(Wt2 + DMODEL * 64);
    float* ss1 = ss0 + 128;
    float* ss2 = ss1 + 256;

    const int* index_map   = (const int*)d_in[21];
    const int* batch_index = (const int*)d_in[22];

    const int nbA = (total + 255) / 256;
    const int nbB = (DMODEL * 256) / 256;
    setup_all<<<nbA + nbB + 1, 256, 0, stream>>>(
        index_map, batch_index, inv, out_t, out_e, total, n0, n0 + n1, nbA,
        (const float*)d_in[3], (const float*)d_in[10], (const float*)d_in[17],
        Wt0, Wt1, Wt2,
        (const float*)d_in[1],  (const float*)d_in[2],
        (const float*)d_in[8],  (const float*)d_in[9],
        (const float*)d_in[15], (const float*)d_in[16],
        ss0, ss1, ss2);

    TypeParams p0{(const float*)d_in[0],  ss0, Wt0,
                  (const float*)d_in[4],  (const float*)d_in[5],  (const float*)d_in[6],
                  n0, 0,       (n0 + 31) / 32};
    TypeParams p1{(const float*)d_in[7],  ss1, Wt1,
                  (const float*)d_in[11], (const float*)d_in[12], (const float*)d_in[13],
                  n1, n0,      (n1 + 31) / 32};
    TypeParams p2{(const float*)d_in[14], ss2, Wt2,
                  (const float*)d_in[18], (const float*)d_in[19], (const float*)d_in[20],
                  n2, n0 + n1, (n2 + 31) / 32};

    const int nb = p0.nb + p1.nb + p2.nb;
    const int lds_size = 4 * 2048 + 32 * 8 * sizeof(float2);

    // real pipeline (exact R5 structure)
    embed_all<false><<<nb, 512, lds_size, stream>>>(p0, p1, p2, inv, out, nb);

    // ablation probe: identical pipeline, LINEAR writes into ws, grid x3 so the
    // dispatch surfaces in rocprof top-5 (duration = 3x one pass). Idempotent.
    const size_t probe_off  = (size_t)32 << 20;
    const size_t probe_need = probe_off + ((size_t)total + 64) * DMODEL * sizeof(float);
    if (ws_size >= probe_need) {
        float* pout = (float*)((char*)d_ws + probe_off);
        embed_all<true><<<nb * 3, 512, lds_size, stream>>>(p0, p1, p2, inv, pout, nb);
    }
}

// Round 12
// 185.756 us; speedup vs baseline: 3.7593x; 3.7593x over previous
//
#include <hip/hip_runtime.h>

#define DMODEL 512
#define EPS_IN 1e-4f
#define EPS_LN 1e-5f
#define CLIPV  5.0f

typedef float f32x4 __attribute__((ext_vector_type(4)));
typedef short s16x8 __attribute__((ext_vector_type(8)));

__device__ __forceinline__ unsigned short f2bf(float f) {
    union { float f; unsigned u; } v; v.f = f;
    unsigned r = v.u + 0x7fffu + ((v.u >> 16) & 1u);
    return (unsigned short)(r >> 16);
}

struct TypeParams {
    const float* x;
    const float* ss;                   // scale[F] then shift[F]
    const unsigned short* Wt;          // [512][KP] bf16, zero-padded K
    const float* b; const float* gamma; const float* beta;
    int n;        // rows of this type
    int offset;   // row offset in concat order
    int nb;       // blocks (32-row tiles)
};

#define REDS 9   // red[] row stride in float2 (padded: 72B -> conflict-free)

// Parts: [A] inv + tbatch/etype, [B] W -> Wt bf16 transpose, [C] scale/shift
__global__ __launch_bounds__(256) void setup_all(
    const int* __restrict__ index_map, const int* __restrict__ batch_index,
    int* __restrict__ inv, float* __restrict__ out_t, float* __restrict__ out_e,
    int total, int n0, int n01, int nbA,
    const float* __restrict__ W0, const float* __restrict__ W1, const float* __restrict__ W2,
    unsigned short* __restrict__ Wt0, unsigned short* __restrict__ Wt1, unsigned short* __restrict__ Wt2,
    const float* __restrict__ mean0, const float* __restrict__ var0,
    const float* __restrict__ mean1, const float* __restrict__ var1,
    const float* __restrict__ mean2, const float* __restrict__ var2,
    float* __restrict__ ss0, float* __restrict__ ss1, float* __restrict__ ss2)
{
    const int nbB = (DMODEL * 256) / 256;
    if (blockIdx.x < (unsigned)nbA) {
        const int j = blockIdx.x * 256 + threadIdx.x;
        if (j >= total) return;
        const int r = index_map[j];
        inv[r] = j;
        out_t[j] = (float)batch_index[r];
        out_e[j] = (r < n0) ? 0.0f : ((r < n01) ? 1.0f : 2.0f);
    } else if (blockIdx.x < (unsigned)(nbA + nbB)) {
        int idx = (blockIdx.x - nbA) * 256 + threadIdx.x;
        const float* W; unsigned short* Wt; int K, Kp;
        if (idx < DMODEL * 64)              { W = W0; Wt = Wt0; K = 64;  Kp = 64; }
        else if (idx < DMODEL * (64 + 128)) { idx -= DMODEL * 64;  W = W1; Wt = Wt1; K = 128; Kp = 128; }
        else                                { idx -= DMODEL * 192; W = W2; Wt = Wt2; K = 48;  Kp = 64; }
        const int nn = idx / Kp, k = idx - nn * Kp;
        const float w = (k < K) ? W[(size_t)k * DMODEL + nn] : 0.0f;
        Wt[idx] = f2bf(w);
    } else {
        const int c = threadIdx.x;
        if (c < 64)  { const float s = rsqrtf(var0[c] + EPS_IN); ss0[c] = s; ss0[64 + c]  = -mean0[c] * s; }
        if (c < 128) { const float s = rsqrtf(var1[c] + EPS_IN); ss1[c] = s; ss1[128 + c] = -mean1[c] * s; }
        if (c < 48)  { const float s = rsqrtf(var2[c] + EPS_IN); ss2[c] = s; ss2[48 + c]  = -mean2[c] * s; }
    }
}

// Block: 32 concat rows x 512 cols, 8 waves. Wave tile: 32 rows x 64 cols (wn).
// OPERAND-SWAPPED MFMA: per lane xrow = m*16+(lane&15), outcol = wn*64+t*16+4g+j.
// LDS A layout: 16B units A[(ks*4+g)*32 + row], XOR-swizzled:
//   byte = ((s*32+row)*16) ^ ((( (s&3)*2 + ((row>>3)&1) )) << 4)
// R11 probe measured 23M bank-conflict cycles/pass: the unswizzled g-chunks sit
// at stride 512B == 0 mod 128B (8 lanes/bank-quad). The XOR spreads the 8
// aliasing lanes over all 8 quads on BOTH the stage write and fragment read.
template<int F, int KP>
__device__ __forceinline__ void embed_body(
    const TypeParams& p, int bid, const int* __restrict__ inv,
    float* __restrict__ out, char* lds)
{
    constexpr int SEG = KP / 8;
    constexpr int NKS = KP / 32;
    const int tid  = threadIdx.x;
    const int lane = tid & 63;
    const int wn   = tid >> 6;     // 0..7 (64-col slice)
    const int l15  = lane & 15;
    const int g    = lane >> 4;    // 0..3
    const int row0 = bid * 32;
    const int n    = p.n;

    float2* red = reinterpret_cast<float2*>(lds + NKS * 2048);  // [32 rows][REDS]

    // ---- stage: InputNorm(x) -> bf16, swizzled fragment-order LDS
    if (tid < 32 * SEG) {
        const int r = tid & 31;
        const int s = tid >> 5;
        const int c = s * 8;
        const int gr = row0 + r;
        s16x8 pk;
#pragma unroll
        for (int jj = 0; jj < 8; ++jj) pk[jj] = 0;
        if (gr < n && c < F) {
            const float4 x0 = *(const float4*)(p.x + (size_t)gr * F + c);
            const float4 x1 = *(const float4*)(p.x + (size_t)gr * F + c + 4);
            const float4 sc0 = *(const float4*)(p.ss + c);
            const float4 sc1 = *(const float4*)(p.ss + c + 4);
            const float4 sh0 = *(const float4*)(p.ss + F + c);
            const float4 sh1 = *(const float4*)(p.ss + F + c + 4);
            float t[8];
            t[0] = fmaf(x0.x, sc0.x, sh0.x); t[1] = fmaf(x0.y, sc0.y, sh0.y);
            t[2] = fmaf(x0.z, sc0.z, sh0.z); t[3] = fmaf(x0.w, sc0.w, sh0.w);
            t[4] = fmaf(x1.x, sc1.x, sh1.x); t[5] = fmaf(x1.y, sc1.y, sh1.y);
            t[6] = fmaf(x1.z, sc1.z, sh1.z); t[7] = fmaf(x1.w, sc1.w, sh1.w);
#pragma unroll
            for (int jj = 0; jj < 8; ++jj)
                pk[jj] = (short)f2bf(fminf(fmaxf(t[jj], -CLIPV), CLIPV));
        }
        const int byte = (tid * 16) ^ ((((s & 3) * 2 + ((r >> 3) & 1))) << 4);
        *reinterpret_cast<s16x8*>(lds + byte) = pk;
    }
    __syncthreads();

    // ---- prefetch inv for this lane's 2 rows (hidden behind MFMA)
    int orow[2];
#pragma unroll
    for (int m = 0; m < 2; ++m) {
        const int rg = row0 + m * 16 + l15;
        orow[m] = (rg < n) ? inv[p.offset + rg] : -1;
    }

    // ---- MFMA (operand-swapped)
    f32x4 acc[2][4];
#pragma unroll
    for (int m = 0; m < 2; ++m)
#pragma unroll
        for (int t = 0; t < 4; ++t) acc[m][t] = (f32x4)0.0f;

    const unsigned short* wtl = p.Wt + (size_t)(wn * 64 + l15) * KP + g * 8;
    const int aswz = (g * 2 + (l15 >> 3)) << 4;   // same XOR for a0 (row=l15) and a1 (row=l15+16)

#pragma unroll
    for (int ks = 0; ks < NKS; ++ks) {
        const int ab = ((((ks * 4 + g) * 32 + l15) * 16)) ^ aswz;
        const s16x8 a0 = *reinterpret_cast<const s16x8*>(lds + ab);
        const s16x8 a1 = *reinterpret_cast<const s16x8*>(lds + ab + 256);
#pragma unroll
        for (int t = 0; t < 4; ++t) {
            const s16x8 wf = *reinterpret_cast<const s16x8*>(wtl + (size_t)t * 16 * KP + ks * 32);
            acc[0][t] = __builtin_amdgcn_mfma_f32_16x16x32_bf16(wf, a0, acc[0][t], 0, 0, 0);
            acc[1][t] = __builtin_amdgcn_mfma_f32_16x16x32_bf16(wf, a1, acc[1][t], 0, 0, 0);
        }
    }

    // ---- bias + ReLU
#pragma unroll
    for (int t = 0; t < 4; ++t) {
        const float4 bb = *(const float4*)(p.b + wn * 64 + t * 16 + g * 4);
#pragma unroll
        for (int m = 0; m < 2; ++m) {
            acc[m][t][0] = fmaxf(acc[m][t][0] + bb.x, 0.0f);
            acc[m][t][1] = fmaxf(acc[m][t][1] + bb.y, 0.0f);
            acc[m][t][2] = fmaxf(acc[m][t][2] + bb.z, 0.0f);
            acc[m][t][3] = fmaxf(acc[m][t][3] + bb.w, 0.0f);
        }
    }

    // ---- LN partials: 2 rows/lane, g-reduce (2 shuffles), cross-wave via red
    {
        float ps[2] = {0.0f, 0.0f}, pq[2] = {0.0f, 0.0f};
#pragma unroll
        for (int m = 0; m < 2; ++m)
#pragma unroll
            for (int t = 0; t < 4; ++t)
#pragma unroll
                for (int j = 0; j < 4; ++j) {
                    const float v = acc[m][t][j];
                    ps[m] += v;
                    pq[m] = fmaf(v, v, pq[m]);
                }
#pragma unroll
        for (int m = 0; m < 2; ++m) {
            ps[m] += __shfl_xor(ps[m], 16, 64);
            pq[m] += __shfl_xor(pq[m], 16, 64);
            ps[m] += __shfl_xor(ps[m], 32, 64);
            pq[m] += __shfl_xor(pq[m], 32, 64);
        }
        if (g == 0) {
#pragma unroll
            for (int m = 0; m < 2; ++m)
                red[(m * 16 + l15) * REDS + wn] = make_float2(ps[m], pq[m]);
        }
    }
    __syncthreads();

    // ---- finish LN + float4 scatter stores
#pragma unroll
    for (int m = 0; m < 2; ++m) {
        const int od = orow[m];
        if (od < 0) continue;
        const int rl = m * 16 + l15;
        float s = 0.0f, q = 0.0f;
#pragma unroll
        for (int wq = 0; wq < 8; ++wq) { const float2 e = red[rl * REDS + wq]; s += e.x; q += e.y; }
        const float mu = s * (1.0f / DMODEL);
        const float vv = fmaxf(q * (1.0f / DMODEL) - mu * mu, 0.0f);
        const float sc = rsqrtf(vv + EPS_LN);
        float* op = out + (size_t)od * DMODEL + wn * 64 + g * 4;
#pragma unroll
        for (int t = 0; t < 4; ++t) {
            const float4 gg = *(const float4*)(p.gamma + wn * 64 + t * 16 + g * 4);
            const float4 ee = *(const float4*)(p.beta  + wn * 64 + t * 16 + g * 4);
            float4 o;
            o.x = fmaf(gg.x * sc, acc[m][t][0] - mu, ee.x);
            o.y = fmaf(gg.y * sc, acc[m][t][1] - mu, ee.y);
            o.z = fmaf(gg.z * sc, acc[m][t][2] - mu, ee.z);
            o.w = fmaf(gg.w * sc, acc[m][t][3] - mu, ee.w);
            *(float4*)(op + t * 16) = o;
        }
    }
}

__global__ __launch_bounds__(512, 4) void embed_all(
    TypeParams p0, TypeParams p1, TypeParams p2,
    const int* __restrict__ inv, float* __restrict__ out)
{
    extern __shared__ char lds[];
    const int bid = blockIdx.x;
    if (bid < p0.nb)                embed_body<64, 64>  (p0, bid, inv, out, lds);
    else if (bid < p0.nb + p1.nb)   embed_body<128, 128>(p1, bid - p0.nb, inv, out, lds);
    else                            embed_body<48, 64>  (p2, bid - p0.nb - p1.nb, inv, out, lds);
}

extern "C" void kernel_launch(void* const* d_in, const int* in_sizes, int n_in,
                              void* d_out, int out_size, void* d_ws, size_t ws_size,
                              hipStream_t stream)
{
    const int F0 = 64, F1 = 128, F2 = 48;
    const int n0 = in_sizes[0]  / F0;
    const int n1 = in_sizes[7]  / F1;
    const int n2 = in_sizes[14] / F2;
    const int total = n0 + n1 + n2;

    float* out   = (float*)d_out;
    float* out_t = out + (size_t)total * DMODEL;
    float* out_e = out_t + total;

    // ws layout: inv[total] ints | Wt0/Wt1/Wt2 bf16 | ss0/ss1/ss2 f32
    int* inv = (int*)d_ws;
    unsigned short* Wt0 = (unsigned short*)((char*)d_ws + (((size_t)total * 4 + 255) & ~(size_t)255));
    unsigned short* Wt1 = Wt0 + DMODEL * 64;
    unsigned short* Wt2 = Wt1 + DMODEL * 128;
    float* ss0 = (float*)(Wt2 + DMODEL * 64);
    float* ss1 = ss0 + 128;
    float* ss2 = ss1 + 256;

    const int* index_map   = (const int*)d_in[21];
    const int* batch_index = (const int*)d_in[22];

    const int nbA = (total + 255) / 256;
    const int nbB = (DMODEL * 256) / 256;
    setup_all<<<nbA + nbB + 1, 256, 0, stream>>>(
        index_map, batch_index, inv, out_t, out_e, total, n0, n0 + n1, nbA,
        (const float*)d_in[3], (const float*)d_in[10], (const float*)d_in[17],
        Wt0, Wt1, Wt2,
        (const float*)d_in[1],  (const float*)d_in[2],
        (const float*)d_in[8],  (const float*)d_in[9],
        (const float*)d_in[15], (const float*)d_in[16],
        ss0, ss1, ss2);

    TypeParams p0{(const float*)d_in[0],  ss0, Wt0,
                  (const float*)d_in[4],  (const float*)d_in[5],  (const float*)d_in[6],
                  n0, 0,       (n0 + 31) / 32};
    TypeParams p1{(const float*)d_in[7],  ss1, Wt1,
                  (const float*)d_in[11], (const float*)d_in[12], (const float*)d_in[13],
                  n1, n0,      (n1 + 31) / 32};
    TypeParams p2{(const float*)d_in[14], ss2, Wt2,
                  (const float*)d_in[18], (const float*)d_in[19], (const float*)d_in[20],
                  n2, n0 + n1, (n2 + 31) / 32};

    const int nb = p0.nb + p1.nb + p2.nb;
    const int lds_size = 4 * 2048 + 32 * REDS * sizeof(float2);  // 8192 + 2304
    embed_all<<<nb, 512, lds_size, stream>>>(p0, p1, p2, inv, out);
}

// Round 13
// 162.479 us; speedup vs baseline: 4.2978x; 1.1433x over previous
//
#include <hip/hip_runtime.h>

#define DMODEL 512
#define EPS_IN 1e-4f
#define EPS_LN 1e-5f
#define CLIPV  5.0f

#define REDS 9   // red[] row stride in float2; 72B -> rl*18 mod 32 spans all 16 even banks

typedef float f32x4 __attribute__((ext_vector_type(4)));
typedef short s16x8 __attribute__((ext_vector_type(8)));

__device__ __forceinline__ unsigned short f2bf(float f) {
    union { float f; unsigned u; } v; v.f = f;
    unsigned r = v.u + 0x7fffu + ((v.u >> 16) & 1u);
    return (unsigned short)(r >> 16);
}

struct TypeParams {
    const float* x;
    const float* ss;                   // scale[F] then shift[F]
    const unsigned short* Wt;          // [512][KP] bf16, zero-padded K
    const float* b; const float* gamma; const float* beta;
    int n;        // rows of this type
    int offset;   // row offset in concat order
    int nb;       // blocks (32 rows each)
};

// Parts: [A] inv + tbatch/etype, [B] W -> Wt bf16 transpose, [C] scale/shift
__global__ __launch_bounds__(256) void setup_all(
    const int* __restrict__ index_map, const int* __restrict__ batch_index,
    int* __restrict__ inv, float* __restrict__ out_t, float* __restrict__ out_e,
    int total, int n0, int n01, int nbA,
    const float* __restrict__ W0, const float* __restrict__ W1, const float* __restrict__ W2,
    unsigned short* __restrict__ Wt0, unsigned short* __restrict__ Wt1, unsigned short* __restrict__ Wt2,
    const float* __restrict__ mean0, const float* __restrict__ var0,
    const float* __restrict__ mean1, const float* __restrict__ var1,
    const float* __restrict__ mean2, const float* __restrict__ var2,
    float* __restrict__ ss0, float* __restrict__ ss1, float* __restrict__ ss2)
{
    const int nbB = (DMODEL * 256) / 256;
    if (blockIdx.x < (unsigned)nbA) {
        const int j = blockIdx.x * 256 + threadIdx.x;
        if (j >= total) return;
        const int r = index_map[j];
        inv[r] = j;
        out_t[j] = (float)batch_index[r];
        out_e[j] = (r < n0) ? 0.0f : ((r < n01) ? 1.0f : 2.0f);
    } else if (blockIdx.x < (unsigned)(nbA + nbB)) {
        int idx = (blockIdx.x - nbA) * 256 + threadIdx.x;
        const float* W; unsigned short* Wt; int K, Kp;
        if (idx < DMODEL * 64)              { W = W0; Wt = Wt0; K = 64;  Kp = 64; }
        else if (idx < DMODEL * (64 + 128)) { idx -= DMODEL * 64;  W = W1; Wt = Wt1; K = 128; Kp = 128; }
        else                                { idx -= DMODEL * 192; W = W2; Wt = Wt2; K = 48;  Kp = 64; }
        const int nn = idx / Kp, k = idx - nn * Kp;
        const float w = (k < K) ? W[(size_t)k * DMODEL + nn] : 0.0f;
        Wt[idx] = f2bf(w);
    } else {
        const int c = threadIdx.x;
        if (c < 64)  { const float s = rsqrtf(var0[c] + EPS_IN); ss0[c] = s; ss0[64 + c]  = -mean0[c] * s; }
        if (c < 128) { const float s = rsqrtf(var1[c] + EPS_IN); ss1[c] = s; ss1[128 + c] = -mean1[c] * s; }
        if (c < 48)  { const float s = rsqrtf(var2[c] + EPS_IN); ss2[c] = s; ss2[48 + c]  = -mean2[c] * s; }
    }
}

// Block: 32 concat rows x 512 cols, 8 waves. Wave tile: 32 rows x 64 cols (wn).
// LDS A layout: fragment-contiguous 16B units: A[(ks*4+g)*32 + row]
//   -> stage writes linear (addr = tid*16), fragment reads linear per quarter-wave.
// EXACT round-5 structure (161 us); single change this round: REDS 8 -> 9.
template<int F, int KP>
__device__ __forceinline__ void embed_body(
    const TypeParams& p, int bid, const int* __restrict__ inv,
    float* __restrict__ out, char* lds)
{
    constexpr int SEG = KP / 8;    // 16B segments per row
    constexpr int NKS = KP / 32;
    const int tid  = threadIdx.x;
    const int lane = tid & 63;
    const int wn   = tid >> 6;     // 0..7 (64-col slice)
    const int l15  = lane & 15;
    const int g    = lane >> 4;    // 0..3
    const int row0 = bid * 32;
    const int n    = p.n;

    float2* red = reinterpret_cast<float2*>(lds + NKS * 2048);  // [32 rows][REDS]

    // ---- stage: InputNorm(x) -> bf16, fragment-order LDS (linear write)
    if (tid < 32 * SEG) {
        const int r = tid & 31;        // row within tile
        const int s = tid >> 5;        // 16B segment = ks*4+g
        const int gr = row0 + r;
        const int c = s * 8;
        s16x8 pk;
#pragma unroll
        for (int jj = 0; jj < 8; ++jj) pk[jj] = 0;
        if (gr < n && c < F) {
            const float4 x0 = *(const float4*)(p.x + (size_t)gr * F + c);
            const float4 x1 = *(const float4*)(p.x + (size_t)gr * F + c + 4);
            const float4 sc0 = *(const float4*)(p.ss + c);
            const float4 sc1 = *(const float4*)(p.ss + c + 4);
            const float4 sh0 = *(const float4*)(p.ss + F + c);
            const float4 sh1 = *(const float4*)(p.ss + F + c + 4);
            float t[8];
            t[0] = fmaf(x0.x, sc0.x, sh0.x); t[1] = fmaf(x0.y, sc0.y, sh0.y);
            t[2] = fmaf(x0.z, sc0.z, sh0.z); t[3] = fmaf(x0.w, sc0.w, sh0.w);
            t[4] = fmaf(x1.x, sc1.x, sh1.x); t[5] = fmaf(x1.y, sc1.y, sh1.y);
            t[6] = fmaf(x1.z, sc1.z, sh1.z); t[7] = fmaf(x1.w, sc1.w, sh1.w);
#pragma unroll
            for (int jj = 0; jj < 8; ++jj)
                pk[jj] = (short)f2bf(fminf(fmaxf(t[jj], -CLIPV), CLIPV));
        }
        *reinterpret_cast<s16x8*>(lds + tid * 16) = pk;
    }
    __syncthreads();

    // ---- prefetch inv for this thread's 8 epilogue rows (hide behind MFMA)
    int orow[8];
#pragma unroll
    for (int m = 0; m < 2; ++m)
#pragma unroll
        for (int j = 0; j < 4; ++j) {
            const int rg = row0 + m * 16 + 4 * g + j;
            orow[m * 4 + j] = (rg < n) ? inv[p.offset + rg] : -1;
        }

    // ---- MFMA: acc[m][t]; rows m*16+(4g+j), cols wn*64 + t*16 + l15
    f32x4 acc[2][4];
#pragma unroll
    for (int m = 0; m < 2; ++m)
#pragma unroll
        for (int t = 0; t < 4; ++t) acc[m][t] = (f32x4)0.0f;

    const unsigned short* wtl = p.Wt + (size_t)(wn * 64 + l15) * KP + g * 8;

#pragma unroll
    for (int ks = 0; ks < NKS; ++ks) {
        const int ab = ((ks * 4 + g) * 32 + l15) * 16;
        const s16x8 a0 = *reinterpret_cast<const s16x8*>(lds + ab);
        const s16x8 a1 = *reinterpret_cast<const s16x8*>(lds + ab + 256);
#pragma unroll
        for (int t = 0; t < 4; ++t) {
            const s16x8 bf = *reinterpret_cast<const s16x8*>(wtl + (size_t)t * 16 * KP + ks * 32);
            acc[0][t] = __builtin_amdgcn_mfma_f32_16x16x32_bf16(a0, bf, acc[0][t], 0, 0, 0);
            acc[1][t] = __builtin_amdgcn_mfma_f32_16x16x32_bf16(a1, bf, acc[1][t], 0, 0, 0);
        }
    }

    // ---- epilogue: bias+ReLU, LayerNorm partials
    float bv[4], gv[4], ev[4];
#pragma unroll
    for (int t = 0; t < 4; ++t) {
        const int col = wn * 64 + t * 16 + l15;
        bv[t] = p.b[col]; gv[t] = p.gamma[col]; ev[t] = p.beta[col];
    }

    {
        float ps[2][4] = {{0}}, pq[2][4] = {{0}};
#pragma unroll
        for (int m = 0; m < 2; ++m)
#pragma unroll
            for (int t = 0; t < 4; ++t)
#pragma unroll
                for (int j = 0; j < 4; ++j) {
                    const float v = fmaxf(acc[m][t][j] + bv[t], 0.0f);
                    ps[m][j] += v;
                    pq[m][j] = fmaf(v, v, pq[m][j]);
                }
#pragma unroll
        for (int off = 1; off < 16; off <<= 1)
#pragma unroll
            for (int m = 0; m < 2; ++m)
#pragma unroll
                for (int j = 0; j < 4; ++j) {
                    ps[m][j] += __shfl_xor(ps[m][j], off, 64);
                    pq[m][j] += __shfl_xor(pq[m][j], off, 64);
                }
        if (l15 == 0) {
#pragma unroll
            for (int m = 0; m < 2; ++m)
#pragma unroll
                for (int j = 0; j < 4; ++j) {
                    const int rl = m * 16 + 4 * g + j;
                    red[rl * REDS + wn] = make_float2(ps[m][j], pq[m][j]);
                }
        }
    }
    __syncthreads();

    // ---- finish LN + scatter stores
#pragma unroll
    for (int m = 0; m < 2; ++m)
#pragma unroll
        for (int j = 0; j < 4; ++j) {
            const int od = orow[m * 4 + j];
            if (od < 0) continue;
            const int rl = m * 16 + 4 * g + j;
            float s = 0.0f, q = 0.0f;
#pragma unroll
            for (int wq = 0; wq < 8; ++wq) { const float2 e = red[rl * REDS + wq]; s += e.x; q += e.y; }
            const float mu = s * (1.0f / DMODEL);
            const float vv = fmaxf(q * (1.0f / DMODEL) - mu * mu, 0.0f);
            const float sc = rsqrtf(vv + EPS_LN);
            float* op = out + (size_t)od * DMODEL + wn * 64 + l15;
#pragma unroll
            for (int t = 0; t < 4; ++t) {
                const float v = fmaxf(acc[m][t][j] + bv[t], 0.0f);
                op[t * 16] = fmaf(gv[t] * sc, v - mu, ev[t]);
            }
        }
}

__global__ __launch_bounds__(512, 4) void embed_all(
    TypeParams p0, TypeParams p1, TypeParams p2,
    const int* __restrict__ inv, float* __restrict__ out)
{
    extern __shared__ char lds[];
    const int bid = blockIdx.x;
    if (bid < p0.nb)                embed_body<64, 64>  (p0, bid, inv, out, lds);
    else if (bid < p0.nb + p1.nb)   embed_body<128, 128>(p1, bid - p0.nb, inv, out, lds);
    else                            embed_body<48, 64>  (p2, bid - p0.nb - p1.nb, inv, out, lds);
}

extern "C" void kernel_launch(void* const* d_in, const int* in_sizes, int n_in,
                              void* d_out, int out_size, void* d_ws, size_t ws_size,
                              hipStream_t stream)
{
    const int F0 = 64, F1 = 128, F2 = 48;
    const int n0 = in_sizes[0]  / F0;
    const int n1 = in_sizes[7]  / F1;
    const int n2 = in_sizes[14] / F2;
    const int total = n0 + n1 + n2;

    float* out   = (float*)d_out;
    float* out_t = out + (size_t)total * DMODEL;
    float* out_e = out_t + total;

    // ws layout: inv[total] ints | Wt0/Wt1/Wt2 bf16 | ss0/ss1/ss2 f32
    int* inv = (int*)d_ws;
    unsigned short* Wt0 = (unsigned short*)((char*)d_ws + (((size_t)total * 4 + 255) & ~(size_t)255));
    unsigned short* Wt1 = Wt0 + DMODEL * 64;
    unsigned short* Wt2 = Wt1 + DMODEL * 128;
    float* ss0 = (float*)(Wt2 + DMODEL * 64);
    float* ss1 = ss0 + 128;
    float* ss2 = ss1 + 256;

    const int* index_map   = (const int*)d_in[21];
    const int* batch_index = (const int*)d_in[22];

    const int nbA = (total + 255) / 256;
    const int nbB = (DMODEL * 256) / 256;
    setup_all<<<nbA + nbB + 1, 256, 0, stream>>>(
        index_map, batch_index, inv, out_t, out_e, total, n0, n0 + n1, nbA,
        (const float*)d_in[3], (const float*)d_in[10], (const float*)d_in[17],
        Wt0, Wt1, Wt2,
        (const float*)d_in[1],  (const float*)d_in[2],
        (const float*)d_in[8],  (const float*)d_in[9],
        (const float*)d_in[15], (const float*)d_in[16],
        ss0, ss1, ss2);

    TypeParams p0{(const float*)d_in[0],  ss0, Wt0,
                  (const float*)d_in[4],  (const float*)d_in[5],  (const float*)d_in[6],
                  n0, 0,       (n0 + 31) / 32};
    TypeParams p1{(const float*)d_in[7],  ss1, Wt1,
                  (const float*)d_in[11], (const float*)d_in[12], (const float*)d_in[13],
                  n1, n0,      (n1 + 31) / 32};
    TypeParams p2{(const float*)d_in[14], ss2, Wt2,
                  (const float*)d_in[18], (const float*)d_in[19], (const float*)d_in[20],
                  n2, n0 + n1, (n2 + 31) / 32};

    const int nb = p0.nb + p1.nb + p2.nb;
    const int lds_size = 4 * 2048 + 32 * REDS * sizeof(float2);  // 8192 + 2304
    embed_all<<<nb, 512, lds_size, stream>>>(p0, p1, p2, inv, out);
}